// Round 2
// baseline (822.501 us; speedup 1.0000x reference)
//
#include <hip/hip_runtime.h>
#include <hip/hip_bf16.h>

#define LL 128
#define BB 32
#define EE 128
#define HH 256
#define NHH 8
#define G3 768   // 3*H
#define IN0 130
#define ETA 100
#define F1 168
#define CLSIN 2304  // 8*256 + 256

typedef _Float16 half_t;
typedef __attribute__((ext_vector_type(2))) _Float16 half2v;

#if defined(__has_builtin)
#if __has_builtin(__builtin_amdgcn_fdot2)
#define HAVE_FDOT2 1
#endif
#endif

__device__ __forceinline__ float fdot2f(half2v a, half2v b, float c) {
#ifdef HAVE_FDOT2
  return __builtin_amdgcn_fdot2(a, b, c, false);
#else
  return c + (float)a.x * (float)b.x + (float)a.y * (float)b.y;
#endif
}

__device__ __forceinline__ float sigmoidf_(float x) { return 1.0f / (1.0f + __expf(-x)); }
__device__ __forceinline__ float tanhf_(float x) { return 1.0f - 2.0f / (__expf(2.0f * x) + 1.0f); }

// ---------------------------------------------------------------------------
// prep: transpose weights, fp32 -> f16 (weights ~N(0,0.05^2): f16 rel err 5e-4)
// ---------------------------------------------------------------------------
__global__ void prep_kernel(
    const float* __restrict__ Wa0,   // [128][256]
    const float* __restrict__ Wih0,  // [768][130]
    const float* __restrict__ Wih1,  // [768][256]
    half_t* __restrict__ Wa0Ta, half_t* __restrict__ Wa0Tb,
    half_t* __restrict__ Wih0T, half_t* __restrict__ Wih1T)
{
  int idx = blockIdx.x * blockDim.x + threadIdx.x;
  const int n1 = 128 * 128, n2 = 128 * 128, n3 = IN0 * G3, n4 = HH * G3;
  if (idx < n1) {
    int d = idx >> 7, k = idx & 127;
    Wa0Ta[idx] = (half_t)Wa0[k * 256 + d];
  } else if (idx < n1 + n2) {
    int j = idx - n1; int d = j >> 7, k = j & 127;
    Wa0Tb[j] = (half_t)Wa0[k * 256 + 128 + d];
  } else if (idx < n1 + n2 + n3) {
    int j = idx - n1 - n2; int d = j / G3, r = j % G3;
    Wih0T[j] = (half_t)Wih0[r * IN0 + d];
  } else if (idx < n1 + n2 + n3 + n4) {
    int j = idx - n1 - n2 - n3; int d = j / G3, r = j % G3;
    Wih1T[j] = (half_t)Wih1[r * HH + d];
  }
}

// ---------------------------------------------------------------------------
// embed gather + U/V factors of the pairwise attention
// U[l,b,k] = e . Wa0[k, :E] ; V[l,b,k] = e . Wa0[k, E:] + ba0[k]
// ---------------------------------------------------------------------------
__global__ void embed_uv_kernel(
    const int* __restrict__ node,             // [L*B]
    const float* __restrict__ table,          // [20001][128]
    const half_t* __restrict__ Wa0Ta,         // [128 d][128 k]
    const half_t* __restrict__ Wa0Tb,
    const float* __restrict__ ba0,            // [128]
    float* __restrict__ e_f32,                // [L*B][128]
    float* __restrict__ U,
    float* __restrict__ V)
{
  int lb = blockIdx.x;
  int k = threadIdx.x;  // 128
  __shared__ float es[EE];
  int n = node[lb];
  float ev = table[(size_t)n * EE + k];
  es[k] = ev;
  e_f32[(size_t)lb * EE + k] = ev;
  __syncthreads();
  float u = 0.f, v = ba0[k];
  #pragma unroll 8
  for (int d = 0; d < EE; ++d) {
    float x = es[d];
    u += (float)Wa0Ta[d * EE + k] * x;
    v += (float)Wa0Tb[d * EE + k] * x;
  }
  U[(size_t)lb * EE + k] = u;
  V[(size_t)lb * EE + k] = v;
}

// ---------------------------------------------------------------------------
// w_pre[i,b,h] = sum_j sum_k Wa1[h,k] * relu(U[j,b,k]+V[i,b,k]) + L*ba1[h]
// ---------------------------------------------------------------------------
__global__ void attn_w_kernel(
    const float* __restrict__ U, const float* __restrict__ V,
    const float* __restrict__ Wa1,  // [8][128]
    const float* __restrict__ ba1,  // [8]
    float* __restrict__ wpre)       // [L][B][8]
{
  int i = blockIdx.x >> 5;
  int b = blockIdx.x & 31;
  int k = threadIdx.x;  // 128
  float vk = V[((size_t)i * BB + b) * EE + k];
  float wa[NHH], acc[NHH];
  #pragma unroll
  for (int h = 0; h < NHH; ++h) { wa[h] = Wa1[h * EE + k]; acc[h] = 0.f; }
  for (int j = 0; j < LL; ++j) {
    float u = U[((size_t)j * BB + b) * EE + k];
    float tv = fmaxf(u + vk, 0.f);
    #pragma unroll
    for (int h = 0; h < NHH; ++h) acc[h] += wa[h] * tv;
  }
  #pragma unroll
  for (int h = 0; h < NHH; ++h) {
    #pragma unroll
    for (int off = 32; off > 0; off >>= 1) acc[h] += __shfl_xor(acc[h], off, 64);
  }
  __shared__ float part[2][NHH];
  int wave = k >> 6;
  if ((k & 63) == 0) {
    #pragma unroll
    for (int h = 0; h < NHH; ++h) part[wave][h] = acc[h];
  }
  __syncthreads();
  if (k < NHH) {
    float w = part[0][k] + part[1][k] + (float)LL * ba1[k];
    wpre[((size_t)i * BB + b) * NHH + k] = w;
  }
}

// softmax over l of (w * mask): masked entries become 0 and STAY in the softmax
__global__ void attn_softmax_kernel(
    const float* __restrict__ wpre, const int* __restrict__ slen,
    float* __restrict__ wsoft)
{
  int b = blockIdx.x >> 3;
  int h = blockIdx.x & 7;
  int l = threadIdx.x;  // 128
  int len = slen[b];
  float x = wpre[((size_t)l * BB + b) * NHH + h];
  float xv = (l < len) ? x : 0.f;
  float m = xv;
  #pragma unroll
  for (int off = 32; off > 0; off >>= 1) m = fmaxf(m, __shfl_xor(m, off, 64));
  __shared__ float sm[2], ss[2];
  int wave = l >> 6;
  if ((l & 63) == 0) sm[wave] = m;
  __syncthreads();
  m = fmaxf(sm[0], sm[1]);
  float e = __expf(xv - m);
  float s = e;
  #pragma unroll
  for (int off = 32; off > 0; off >>= 1) s += __shfl_xor(s, off, 64);
  if ((l & 63) == 0) ss[wave] = s;
  __syncthreads();
  s = ss[0] + ss[1];
  wsoft[((size_t)l * BB + b) * NHH + h] = e / s;
}

// ---------------------------------------------------------------------------
// gi0[lb, :] = [e, ts] @ Wih0.T + bih0   (4 lb's per block to amortize weights)
// ---------------------------------------------------------------------------
__global__ void gi0_kernel(
    const float* __restrict__ e_f32, const float* __restrict__ ts,
    const half_t* __restrict__ WT,   // [130][768]
    const float* __restrict__ bih,
    float* __restrict__ gi)
{
  int lb0 = blockIdx.x * 4;
  int tid = threadIdx.x;  // 256
  __shared__ float xs[4][IN0];
  if (tid < 128) {
    #pragma unroll
    for (int q = 0; q < 4; ++q) xs[q][tid] = e_f32[(size_t)(lb0 + q) * EE + tid];
  } else if (tid < 132) {
    int q = tid - 128;
    xs[q][128] = ts[(lb0 + q) * 2];
    xs[q][129] = ts[(lb0 + q) * 2 + 1];
  }
  __syncthreads();
  float b0 = bih[tid], b1 = bih[256 + tid], b2 = bih[512 + tid];
  float a[4][3];
  #pragma unroll
  for (int q = 0; q < 4; ++q) { a[q][0] = b0; a[q][1] = b1; a[q][2] = b2; }
  for (int d = 0; d < IN0; ++d) {
    const half_t* wp = WT + (size_t)d * G3;
    float w0 = (float)wp[tid], w1 = (float)wp[256 + tid], w2 = (float)wp[512 + tid];
    #pragma unroll
    for (int q = 0; q < 4; ++q) {
      float x = xs[q][d];
      a[q][0] += w0 * x; a[q][1] += w1 * x; a[q][2] += w2 * x;
    }
  }
  #pragma unroll
  for (int q = 0; q < 4; ++q) {
    float* gp = gi + (size_t)(lb0 + q) * G3;
    gp[tid] = a[q][0]; gp[256 + tid] = a[q][1]; gp[512 + tid] = a[q][2];
  }
}

__global__ void gi1_kernel(
    const float* __restrict__ out0,  // [L*B][256]
    const half_t* __restrict__ WT,   // [256][768]
    const float* __restrict__ bih,
    float* __restrict__ gi)
{
  int lb0 = blockIdx.x * 4;
  int tid = threadIdx.x;  // 256
  __shared__ float xs[4][HH];
  #pragma unroll
  for (int q = 0; q < 4; ++q) xs[q][tid] = out0[(size_t)(lb0 + q) * HH + tid];
  __syncthreads();
  float b0 = bih[tid], b1 = bih[256 + tid], b2 = bih[512 + tid];
  float a[4][3];
  #pragma unroll
  for (int q = 0; q < 4; ++q) { a[q][0] = b0; a[q][1] = b1; a[q][2] = b2; }
  for (int d = 0; d < HH; ++d) {
    const half_t* wp = WT + (size_t)d * G3;
    float w0 = (float)wp[tid], w1 = (float)wp[256 + tid], w2 = (float)wp[512 + tid];
    #pragma unroll
    for (int q = 0; q < 4; ++q) {
      float x = xs[q][d];
      a[q][0] += w0 * x; a[q][1] += w1 * x; a[q][2] += w2 * x;
    }
  }
  #pragma unroll
  for (int q = 0; q < 4; ++q) {
    float* gp = gi + (size_t)(lb0 + q) * G3;
    gp[tid] = a[q][0]; gp[256 + tid] = a[q][1]; gp[512 + tid] = a[q][2];
  }
}

// ---------------------------------------------------------------------------
// GRU scan: one block per batch element, Whh resident in registers as f16.
// 512 threads: thread t owns full row t (rows 0..511 = r/z gates, 128 half2)
// plus half of row 512+(t>>1) (n gate, 64 half2).
// ---------------------------------------------------------------------------
__global__ __launch_bounds__(512, 2) void gru_scan_kernel(
    const float* __restrict__ Whh,           // [768][256] f32
    const float* __restrict__ bhh,           // [768]
    const float* __restrict__ gi,            // [L][B][768]
    const int* __restrict__ slen,            // [B]
    float* __restrict__ out,                 // [L][B][256]
    float* __restrict__ hT)                  // [B][256]
{
  const int b = blockIdx.x;
  const int tid = threadIdx.x;
  __shared__ half2v h2s[HH / 2];
  __shared__ float hf[HH];
  __shared__ float grz[512];
  __shared__ float gn[HH];

  half2v wA[128];
  {
    const float4* rowp = (const float4*)(Whh + (size_t)tid * HH);  // 64 float4
    #pragma unroll
    for (int i = 0; i < 64; ++i) {
      float4 f = rowp[i];
      half2v w0; w0.x = (half_t)f.x; w0.y = (half_t)f.y;
      half2v w1; w1.x = (half_t)f.z; w1.y = (half_t)f.w;
      wA[2 * i] = w0; wA[2 * i + 1] = w1;
    }
  }
  const int kb = (tid & 1) * 64;  // half2 offset of this thread's half-row
  half2v wB[64];
  {
    const float4* rowp = (const float4*)(Whh + (size_t)(512 + (tid >> 1)) * HH + 2 * kb);
    #pragma unroll
    for (int i = 0; i < 32; ++i) {
      float4 f = rowp[i];
      half2v w0; w0.x = (half_t)f.x; w0.y = (half_t)f.y;
      half2v w1; w1.x = (half_t)f.z; w1.y = (half_t)f.w;
      wB[2 * i] = w0; wB[2 * i + 1] = w1;
    }
  }

  float bhr = 0.f, bhz = 0.f, bhn = 0.f;
  const int len = slen[b];
  if (tid < HH) {
    bhr = bhh[tid];
    bhz = bhh[HH + tid];
    bhn = bhh[2 * HH + tid];
    hf[tid] = 0.f;
  }
  if (tid < HH / 2) { half2v z0; z0.x = (half_t)0.f; z0.y = (half_t)0.f; h2s[tid] = z0; }
  __syncthreads();

  #pragma unroll 1
  for (int t = 0; t < LL; ++t) {
    float acc = 0.f;
    #pragma unroll
    for (int i = 0; i < 128; ++i) acc = fdot2f(wA[i], h2s[i], acc);
    float acc2 = 0.f;
    #pragma unroll
    for (int i = 0; i < 64; ++i) acc2 = fdot2f(wB[i], h2s[kb + i], acc2);
    acc2 += __shfl_xor(acc2, 1, 64);
    grz[tid] = acc;
    if ((tid & 1) == 0) gn[tid >> 1] = acc2;
    __syncthreads();
    if (tid < HH) {
      const float* gip = gi + ((size_t)t * BB + b) * G3;
      float r = sigmoidf_(gip[tid] + grz[tid] + bhr);
      float z = sigmoidf_(gip[HH + tid] + grz[HH + tid] + bhz);
      float n = tanhf_(gip[2 * HH + tid] + r * (gn[tid] + bhn));
      float hold = hf[tid];
      float hnew = (1.f - z) * n + z * hold;
      bool valid = t < len;
      float hkeep = valid ? hnew : hold;
      hf[tid] = hkeep;
      ((half_t*)h2s)[tid] = (half_t)hkeep;
      out[((size_t)t * BB + b) * HH + tid] = valid ? hnew : 0.f;
    }
    __syncthreads();
  }
  if (tid < HH) hT[(size_t)b * HH + tid] = hf[tid];
}

// ---------------------------------------------------------------------------
// ctx[b, h*256+d] = sum_l wsoft[l,b,h] * out1[l,b,d]
// ---------------------------------------------------------------------------
__global__ void ctx_kernel(
    const float* __restrict__ wsoft, const float* __restrict__ out1,
    float* __restrict__ ctx)
{
  int b = blockIdx.x >> 3, h = blockIdx.x & 7;
  int d = threadIdx.x;  // 256
  float acc = 0.f;
  for (int l = 0; l < LL; ++l) {
    float w = wsoft[((size_t)l * BB + b) * NHH + h];
    acc += w * out1[((size_t)l * BB + b) * HH + d];
  }
  ctx[(size_t)b * (NHH * HH) + h * HH + d] = acc;
}

// ---------------------------------------------------------------------------
// final MLP: z = selu([ctx, hT] @ Wf0.T + bf0); logits = z @ Wf1.T + bf1;
// out = log_softmax(logits)
// ---------------------------------------------------------------------------
__global__ __launch_bounds__(512) void final_kernel(
    const float* __restrict__ ctx, const float* __restrict__ hT,
    const float* __restrict__ Wf0,   // [168][2304]
    const float* __restrict__ bf0,
    const float* __restrict__ Wf1,   // [100][168]
    const float* __restrict__ bf1,
    float* __restrict__ outp)        // [B][100]
{
  int b = blockIdx.x;
  int tid = threadIdx.x;
  int wave = tid >> 6, lane = tid & 63;
  __shared__ float4 xs4[CLSIN / 4];
  __shared__ float zs[F1];
  __shared__ float ls[ETA];
  float* xs = (float*)xs4;
  for (int i = tid; i < NHH * HH; i += 512) xs[i] = ctx[(size_t)b * (NHH * HH) + i];
  if (tid < HH) xs[NHH * HH + tid] = hT[(size_t)b * HH + tid];
  __syncthreads();
  for (int r = wave; r < F1; r += 8) {
    const float4* wp = (const float4*)(Wf0 + (size_t)r * CLSIN);
    float acc = 0.f;
    #pragma unroll
    for (int i = 0; i < CLSIN / 4 / 64; ++i) {  // 9
      float4 w = wp[lane + 64 * i];
      float4 x = xs4[lane + 64 * i];
      acc += w.x * x.x + w.y * x.y + w.z * x.z + w.w * x.w;
    }
    #pragma unroll
    for (int off = 32; off > 0; off >>= 1) acc += __shfl_xor(acc, off, 64);
    if (lane == 0) {
      float x = acc + bf0[r];
      const float alpha = 1.6732632423543772f, scale = 1.0507009873554805f;
      zs[r] = scale * (x > 0.f ? x : alpha * (__expf(x) - 1.f));
    }
  }
  __syncthreads();
  for (int r = wave; r < ETA; r += 8) {
    float acc = 0.f;
    for (int k = lane; k < F1; k += 64) acc += Wf1[r * F1 + k] * zs[k];
    #pragma unroll
    for (int off = 32; off > 0; off >>= 1) acc += __shfl_xor(acc, off, 64);
    if (lane == 0) ls[r] = acc + bf1[r];
  }
  __syncthreads();
  if (wave == 0) {
    float v0 = (lane < ETA) ? ls[lane] : -1e30f;
    float v1 = (lane + 64 < ETA) ? ls[lane + 64] : -1e30f;
    float m = fmaxf(v0, v1);
    #pragma unroll
    for (int off = 32; off > 0; off >>= 1) m = fmaxf(m, __shfl_xor(m, off, 64));
    float s = __expf(v0 - m) + __expf(v1 - m);
    #pragma unroll
    for (int off = 32; off > 0; off >>= 1) s += __shfl_xor(s, off, 64);
    float lse = m + __logf(s);
    if (lane < ETA) outp[(size_t)b * ETA + lane] = v0 - lse;
    if (lane + 64 < ETA) outp[(size_t)b * ETA + lane + 64] = v1 - lse;
  }
}

extern "C" void kernel_launch(void* const* d_in, const int* in_sizes, int n_in,
                              void* d_out, int out_size, void* d_ws, size_t ws_size,
                              hipStream_t stream) {
  const int*   node  = (const int*)d_in[0];
  const float* ts    = (const float*)d_in[1];
  const int*   slen  = (const int*)d_in[2];
  const float* table = (const float*)d_in[3];
  const float* Wih0  = (const float*)d_in[4];
  const float* Whh0  = (const float*)d_in[5];
  const float* bih0  = (const float*)d_in[6];
  const float* bhh0  = (const float*)d_in[7];
  const float* Wih1  = (const float*)d_in[8];
  const float* Whh1  = (const float*)d_in[9];
  const float* bih1  = (const float*)d_in[10];
  const float* bhh1  = (const float*)d_in[11];
  const float* Wa0   = (const float*)d_in[12];
  const float* ba0   = (const float*)d_in[13];
  const float* Wa1   = (const float*)d_in[14];
  const float* ba1   = (const float*)d_in[15];
  const float* Wf0   = (const float*)d_in[16];
  const float* bf0   = (const float*)d_in[17];
  const float* Wf1   = (const float*)d_in[18];
  const float* bf1   = (const float*)d_in[19];

  char* ws = (char*)d_ws;
  size_t off = 0;
  auto alloc = [&](size_t n) { void* p = (void*)(ws + off); off += (n + 255) & ~(size_t)255; return p; };

  float* e_f32 = (float*)alloc((size_t)LL * BB * EE * 4);
  float* U     = (float*)alloc((size_t)LL * BB * EE * 4);
  float* V     = (float*)alloc((size_t)LL * BB * EE * 4);
  float* gi    = (float*)alloc((size_t)LL * BB * G3 * 4);   // reused for both layers
  float* out0  = (float*)alloc((size_t)LL * BB * HH * 4);
  float* out1  = (float*)alloc((size_t)LL * BB * HH * 4);
  float* hTb   = (float*)alloc((size_t)BB * HH * 4);
  float* wpre  = (float*)alloc((size_t)LL * BB * NHH * 4);
  float* wsoft = (float*)alloc((size_t)LL * BB * NHH * 4);
  float* ctxb  = (float*)alloc((size_t)BB * NHH * HH * 4);
  half_t* Wa0Ta = (half_t*)alloc((size_t)128 * 128 * 2);
  half_t* Wa0Tb = (half_t*)alloc((size_t)128 * 128 * 2);
  half_t* Wih0T = (half_t*)alloc((size_t)IN0 * G3 * 2);
  half_t* Wih1T = (half_t*)alloc((size_t)HH * G3 * 2);
  if (off > ws_size) return;  // workspace too small: fail visibly

  const int prep_total = 128 * 128 + 128 * 128 + IN0 * G3 + HH * G3;
  prep_kernel<<<(prep_total + 255) / 256, 256, 0, stream>>>(Wa0, Wih0, Wih1, Wa0Ta, Wa0Tb, Wih0T, Wih1T);
  embed_uv_kernel<<<LL * BB, 128, 0, stream>>>(node, table, Wa0Ta, Wa0Tb, ba0, e_f32, U, V);
  attn_w_kernel<<<LL * BB, 128, 0, stream>>>(U, V, Wa1, ba1, wpre);
  attn_softmax_kernel<<<BB * NHH, 128, 0, stream>>>(wpre, slen, wsoft);
  gi0_kernel<<<LL * BB / 4, 256, 0, stream>>>(e_f32, ts, Wih0T, bih0, gi);
  gru_scan_kernel<<<BB, 512, 0, stream>>>(Whh0, bhh0, gi, slen, out0, hTb);
  gi1_kernel<<<LL * BB / 4, 256, 0, stream>>>(out0, Wih1T, bih1, gi);
  gru_scan_kernel<<<BB, 512, 0, stream>>>(Whh1, bhh1, gi, slen, out1, hTb);
  ctx_kernel<<<BB * NHH, 256, 0, stream>>>(wsoft, out1, ctxb);
  final_kernel<<<BB, 512, 0, stream>>>(ctxb, hTb, Wf0, bf0, Wf1, bf1, (float*)d_out);
}

// Round 3
// 592.681 us; speedup vs baseline: 1.3878x; 1.3878x over previous
//
#include <hip/hip_runtime.h>
#include <hip/hip_bf16.h>

#define LL 128
#define BB 32
#define EE 128
#define HH 256
#define NHH 8
#define G3 768   // 3*H
#define IN0 130
#define ETA 100
#define F1 168
#define CLSIN 2304  // 8*256 + 256

typedef _Float16 half_t;
typedef __attribute__((ext_vector_type(2))) _Float16 half2v;

union F4H { float4 f4; half2v h2[4]; };

#if defined(__has_builtin)
#if __has_builtin(__builtin_amdgcn_fdot2)
#define HAVE_FDOT2 1
#endif
#endif

__device__ __forceinline__ float fdot2f(half2v a, half2v b, float c) {
#ifdef HAVE_FDOT2
  return __builtin_amdgcn_fdot2(a, b, c, false);
#else
  return c + (float)a.x * (float)b.x + (float)a.y * (float)b.y;
#endif
}

// LDS-only barrier: skip the compiler's vmcnt(0) drain (no cross-thread
// global-memory dependencies at our barriers; same-thread global loads get
// their own compiler-inserted waitcnts before use).
#define BARRIER_LDS() __asm__ volatile("s_waitcnt lgkmcnt(0)\n\ts_barrier" ::: "memory")

__device__ __forceinline__ float sigmoidf_(float x) { return 1.0f / (1.0f + __expf(-x)); }
__device__ __forceinline__ float tanhf_(float x) { return 1.0f - 2.0f / (__expf(2.0f * x) + 1.0f); }

// ---------------------------------------------------------------------------
// prep: weight repack fp32 -> f16 (weights ~N(0,0.05^2): f16 rel err 5e-4)
//  Wa0Ta/Wa0Tb: [d][k] transposed halves of Wa0
//  Wih0T2: [65 d2][768 r] half2 pairs along input dim (128,129 = ts cols)
//  Wih1T2: [128 d2][768 r] half2
//  Whh0h/Whh1h: straight f16 copies, [768][256]
// ---------------------------------------------------------------------------
__global__ void prep_kernel(
    const float* __restrict__ Wa0, const float* __restrict__ Wih0,
    const float* __restrict__ Wih1, const float* __restrict__ Whh0,
    const float* __restrict__ Whh1,
    half_t* __restrict__ Wa0Ta, half_t* __restrict__ Wa0Tb,
    half2v* __restrict__ Wih0T2, half2v* __restrict__ Wih1T2,
    half_t* __restrict__ Whh0h, half_t* __restrict__ Whh1h)
{
  int idx = blockIdx.x * blockDim.x + threadIdx.x;
  const int n1 = 16384, n2 = 16384, n3 = 65 * 768, n4 = 128 * 768, n5 = 196608;
  if (idx < n1) {
    int d = idx >> 7, k = idx & 127;
    Wa0Ta[idx] = (half_t)Wa0[k * 256 + d];
  } else if ((idx -= n1) < n2) {
    int d = idx >> 7, k = idx & 127;
    Wa0Tb[idx] = (half_t)Wa0[k * 256 + 128 + d];
  } else if ((idx -= n2) < n3) {
    int d2 = idx / 768, r = idx % 768;
    half2v w; w.x = (half_t)Wih0[r * IN0 + 2 * d2]; w.y = (half_t)Wih0[r * IN0 + 2 * d2 + 1];
    Wih0T2[idx] = w;
  } else if ((idx -= n3) < n4) {
    int d2 = idx / 768, r = idx % 768;
    half2v w; w.x = (half_t)Wih1[r * HH + 2 * d2]; w.y = (half_t)Wih1[r * HH + 2 * d2 + 1];
    Wih1T2[idx] = w;
  } else if ((idx -= n4) < n5) {
    Whh0h[idx] = (half_t)Whh0[idx];
  } else if ((idx -= n5) < n5) {
    Whh1h[idx] = (half_t)Whh1[idx];
  }
}

// ---------------------------------------------------------------------------
// embed gather + U/V factors of the pairwise attention
// U[l,b,k] = e . Wa0[k, :E] ; V[l,b,k] = e . Wa0[k, E:] + ba0[k]
// also writes e as packed half2 pairs for gi0
// ---------------------------------------------------------------------------
__global__ void embed_uv_kernel(
    const int* __restrict__ node,             // [L*B]
    const float* __restrict__ table,          // [20001][128]
    const half_t* __restrict__ Wa0Ta,         // [128 d][128 k]
    const half_t* __restrict__ Wa0Tb,
    const float* __restrict__ ba0,            // [128]
    half2v* __restrict__ e_h2,                // [L*B][64]
    float* __restrict__ U,
    float* __restrict__ V)
{
  int lb = blockIdx.x;
  int k = threadIdx.x;  // 128
  __shared__ float es[EE];
  int n = node[lb];
  float ev = table[(size_t)n * EE + k];
  es[k] = ev;
  __syncthreads();
  if (k < 64) {
    half2v p; p.x = (half_t)es[2 * k]; p.y = (half_t)es[2 * k + 1];
    e_h2[(size_t)lb * 64 + k] = p;
  }
  float u = 0.f, v = ba0[k];
  #pragma unroll 8
  for (int d = 0; d < EE; ++d) {
    float x = es[d];
    u += (float)Wa0Ta[d * EE + k] * x;
    v += (float)Wa0Tb[d * EE + k] * x;
  }
  U[(size_t)lb * EE + k] = u;
  V[(size_t)lb * EE + k] = v;
}

// ---------------------------------------------------------------------------
// w_pre[i,b,h] = sum_j sum_k Wa1[h,k] * relu(U[j,b,k]+V[i,b,k]) + L*ba1[h]
// 4 i's per block to amortize U reads
// ---------------------------------------------------------------------------
__global__ __launch_bounds__(128) void attn_w_kernel(
    const float* __restrict__ U, const float* __restrict__ V,
    const float* __restrict__ Wa1,  // [8][128]
    const float* __restrict__ ba1,  // [8]
    float* __restrict__ wpre)       // [L][B][8]
{
  int ig = blockIdx.x >> 5;
  int b = blockIdx.x & 31;
  int i0 = ig * 4;
  int k = threadIdx.x;  // 128
  float vk[4];
  #pragma unroll
  for (int ii = 0; ii < 4; ++ii) vk[ii] = V[((size_t)(i0 + ii) * BB + b) * EE + k];
  float wa[NHH], acc[4][NHH];
  #pragma unroll
  for (int h = 0; h < NHH; ++h) wa[h] = Wa1[h * EE + k];
  #pragma unroll
  for (int ii = 0; ii < 4; ++ii)
    #pragma unroll
    for (int h = 0; h < NHH; ++h) acc[ii][h] = 0.f;
  for (int j = 0; j < LL; ++j) {
    float u = U[((size_t)j * BB + b) * EE + k];
    #pragma unroll
    for (int ii = 0; ii < 4; ++ii) {
      float tv = fmaxf(u + vk[ii], 0.f);
      #pragma unroll
      for (int h = 0; h < NHH; ++h) acc[ii][h] += wa[h] * tv;
    }
  }
  __shared__ float part[2][32];
  int wave = k >> 6, lane = k & 63;
  #pragma unroll
  for (int ii = 0; ii < 4; ++ii)
    #pragma unroll
    for (int h = 0; h < NHH; ++h) {
      float a = acc[ii][h];
      #pragma unroll
      for (int off = 32; off > 0; off >>= 1) a += __shfl_xor(a, off, 64);
      if (lane == 0) part[wave][ii * 8 + h] = a;
    }
  __syncthreads();
  if (k < 32) {
    int ii = k >> 3, h = k & 7;
    float w = part[0][k] + part[1][k] + (float)LL * ba1[h];
    wpre[((size_t)(i0 + ii) * BB + b) * NHH + h] = w;
  }
}

// softmax over l of (w * mask): masked entries become 0 and STAY in the softmax
__global__ void attn_softmax_kernel(
    const float* __restrict__ wpre, const int* __restrict__ slen,
    float* __restrict__ wsoft)
{
  int b = blockIdx.x >> 3;
  int h = blockIdx.x & 7;
  int l = threadIdx.x;  // 128
  int len = slen[b];
  float x = wpre[((size_t)l * BB + b) * NHH + h];
  float xv = (l < len) ? x : 0.f;
  float m = xv;
  #pragma unroll
  for (int off = 32; off > 0; off >>= 1) m = fmaxf(m, __shfl_xor(m, off, 64));
  __shared__ float sm[2], ss[2];
  int wave = l >> 6;
  if ((l & 63) == 0) sm[wave] = m;
  __syncthreads();
  m = fmaxf(sm[0], sm[1]);
  float e = __expf(xv - m);
  float s = e;
  #pragma unroll
  for (int off = 32; off > 0; off >>= 1) s += __shfl_xor(s, off, 64);
  if ((l & 63) == 0) ss[wave] = s;
  __syncthreads();
  s = ss[0] + ss[1];
  wsoft[((size_t)l * BB + b) * NHH + h] = e / s;
}

// ---------------------------------------------------------------------------
// gi0: [e, ts] @ Wih0.T + bih0, 8 lb per block, v_dot2 on packed pairs
// ---------------------------------------------------------------------------
__global__ __launch_bounds__(256) void gi0_kernel(
    const half2v* __restrict__ e_h2, const float* __restrict__ ts,
    const half2v* __restrict__ W2,   // [65][768]
    const float* __restrict__ bih,
    float* __restrict__ gi)
{
  int lb0 = blockIdx.x * 8;
  int tid = threadIdx.x;  // 256
  __shared__ half2v xs2[8][66];
  for (int idx = tid; idx < 512; idx += 256) {
    int q = idx >> 6, d2 = idx & 63;
    xs2[q][d2] = e_h2[(size_t)(lb0 + q) * 64 + d2];
  }
  if (tid < 8) {
    half2v t2; t2.x = (half_t)ts[(lb0 + tid) * 2]; t2.y = (half_t)ts[(lb0 + tid) * 2 + 1];
    xs2[tid][64] = t2;
  }
  __syncthreads();
  float acc[8][3];
  #pragma unroll
  for (int q = 0; q < 8; ++q) { acc[q][0] = 0.f; acc[q][1] = 0.f; acc[q][2] = 0.f; }
  for (int d2 = 0; d2 < 65; ++d2) {
    half2v w0 = W2[d2 * 768 + tid];
    half2v w1 = W2[d2 * 768 + 256 + tid];
    half2v w2 = W2[d2 * 768 + 512 + tid];
    #pragma unroll
    for (int q = 0; q < 8; ++q) {
      half2v x = xs2[q][d2];
      acc[q][0] = fdot2f(w0, x, acc[q][0]);
      acc[q][1] = fdot2f(w1, x, acc[q][1]);
      acc[q][2] = fdot2f(w2, x, acc[q][2]);
    }
  }
  float b0 = bih[tid], b1 = bih[256 + tid], b2 = bih[512 + tid];
  #pragma unroll
  for (int q = 0; q < 8; ++q) {
    float* gp = gi + (size_t)(lb0 + q) * G3;
    gp[tid] = acc[q][0] + b0; gp[256 + tid] = acc[q][1] + b1; gp[512 + tid] = acc[q][2] + b2;
  }
}

// ---------------------------------------------------------------------------
// gi1: out0 @ Wih1.T + bih1, 8 lb per block
// ---------------------------------------------------------------------------
__global__ __launch_bounds__(256) void gi1_kernel(
    const float* __restrict__ out0,  // [L*B][256]
    const half2v* __restrict__ W2,   // [128][768]
    const float* __restrict__ bih,
    float* __restrict__ gi)
{
  int lb0 = blockIdx.x * 8;
  int tid = threadIdx.x;  // 256
  __shared__ half2v xs2[8][128];
  for (int idx = tid; idx < 1024; idx += 256) {
    int q = idx >> 7, d2 = idx & 127;
    float2 v = ((const float2*)(out0 + (size_t)(lb0 + q) * HH))[d2];
    half2v x; x.x = (half_t)v.x; x.y = (half_t)v.y;
    xs2[q][d2] = x;
  }
  __syncthreads();
  float acc[8][3];
  #pragma unroll
  for (int q = 0; q < 8; ++q) { acc[q][0] = 0.f; acc[q][1] = 0.f; acc[q][2] = 0.f; }
  for (int d2 = 0; d2 < 128; ++d2) {
    half2v w0 = W2[d2 * 768 + tid];
    half2v w1 = W2[d2 * 768 + 256 + tid];
    half2v w2 = W2[d2 * 768 + 512 + tid];
    #pragma unroll
    for (int q = 0; q < 8; ++q) {
      half2v x = xs2[q][d2];
      acc[q][0] = fdot2f(w0, x, acc[q][0]);
      acc[q][1] = fdot2f(w1, x, acc[q][1]);
      acc[q][2] = fdot2f(w2, x, acc[q][2]);
    }
  }
  float b0 = bih[tid], b1 = bih[256 + tid], b2 = bih[512 + tid];
  #pragma unroll
  for (int q = 0; q < 8; ++q) {
    float* gp = gi + (size_t)(lb0 + q) * G3;
    gp[tid] = acc[q][0] + b0; gp[256 + tid] = acc[q][1] + b1; gp[512 + tid] = acc[q][2] + b2;
  }
}

// ---------------------------------------------------------------------------
// GRU scan: one block per batch element. Thread (g = tid>>2, s = tid&3)
// holds rows 6g..6g+5 of Whh restricted to k-slice [64s, 64s+64) in registers
// (192 half2 VGPRs). Phase 1: partial dots (reads only 64 halfs of h from
// LDS = 8 b128). Phase 2 (tid<256): 4-way partial reduce (3 b128) + gates.
// ---------------------------------------------------------------------------
__global__ __launch_bounds__(512, 2) void gru_scan_kernel(
    const half_t* __restrict__ Whhh,         // [768][256] f16
    const float* __restrict__ bhh,           // [768]
    const float* __restrict__ gi,            // [L][B][768]
    const int* __restrict__ slen,            // [B]
    float* __restrict__ out,                 // [L][B][256]
    float* __restrict__ hT)                  // [B][256]
{
  const int b = blockIdx.x;
  const int tid = threadIdx.x;
  const int s = tid & 3;
  const int g = tid >> 2;
  __shared__ __align__(16) half2v h2s[128];  // h as f16, 256 halfs
  __shared__ float4 partials[768];           // [row] -> 4 slice partials

  half2v wReg[6][32];
  #pragma unroll
  for (int r = 0; r < 6; ++r) {
    const float4* wp = (const float4*)(Whhh + (size_t)(6 * g + r) * HH + 64 * s);
    #pragma unroll
    for (int j = 0; j < 8; ++j) {
      F4H v; v.f4 = wp[j];
      wReg[r][4 * j + 0] = v.h2[0]; wReg[r][4 * j + 1] = v.h2[1];
      wReg[r][4 * j + 2] = v.h2[2]; wReg[r][4 * j + 3] = v.h2[3];
    }
  }

  const int len = slen[b];
  float bhr = 0.f, bhz = 0.f, bhn = 0.f, hold = 0.f;
  if (tid < HH) {
    bhr = bhh[tid]; bhz = bhh[HH + tid]; bhn = bhh[2 * HH + tid];
  }
  if (tid < 128) { half2v z0; z0.x = (half_t)0.f; z0.y = (half_t)0.f; h2s[tid] = z0; }
  __syncthreads();

  const float* gib = gi + (size_t)b * G3;
  float* outb = out + (size_t)b * HH;

  #pragma unroll 1
  for (int t = 0; t < LL; ++t) {
    // issue gi loads early; latency hides under the dot phase
    float g0 = 0.f, g1 = 0.f, g2 = 0.f;
    if (tid < HH) {
      const float* gp = gib + (size_t)t * (BB * G3);
      g0 = gp[tid]; g1 = gp[HH + tid]; g2 = gp[2 * HH + tid];
    }
    float acc[6] = {0.f, 0.f, 0.f, 0.f, 0.f, 0.f};
    const float4* hp = (const float4*)h2s;
    #pragma unroll
    for (int c = 0; c < 4; ++c) {
      F4H ha, hb;
      ha.f4 = hp[8 * s + 2 * c];
      hb.f4 = hp[8 * s + 2 * c + 1];
      half2v hh[8] = {ha.h2[0], ha.h2[1], ha.h2[2], ha.h2[3],
                      hb.h2[0], hb.h2[1], hb.h2[2], hb.h2[3]};
      #pragma unroll
      for (int r = 0; r < 6; ++r) {
        #pragma unroll
        for (int i = 0; i < 8; ++i)
          acc[r] = fdot2f(wReg[r][8 * c + i], hh[i], acc[r]);
      }
    }
    #pragma unroll
    for (int r = 0; r < 6; ++r)
      ((float*)partials)[(6 * g + r) * 4 + s] = acc[r];
    BARRIER_LDS();
    if (tid < HH) {
      float4 pr = partials[tid];
      float4 pz = partials[HH + tid];
      float4 pn = partials[2 * HH + tid];
      float srz = (pr.x + pr.y) + (pr.z + pr.w);
      float sz  = (pz.x + pz.y) + (pz.z + pz.w);
      float sn  = (pn.x + pn.y) + (pn.z + pn.w);
      float r_ = sigmoidf_(g0 + srz + bhr);
      float z_ = sigmoidf_(g1 + sz + bhz);
      float n_ = tanhf_(g2 + r_ * (sn + bhn));
      float hnew = (1.f - z_) * n_ + z_ * hold;
      bool valid = t < len;
      hold = valid ? hnew : hold;
      ((half_t*)h2s)[tid] = (half_t)hold;
      outb[(size_t)t * (BB * HH) + tid] = valid ? hnew : 0.f;
    }
    BARRIER_LDS();
  }
  if (tid < HH) hT[(size_t)b * HH + tid] = hold;
}

// ---------------------------------------------------------------------------
// ctx[b, h*256+d] = sum_l wsoft[l,b,h] * out1[l,b,d]
// ---------------------------------------------------------------------------
__global__ void ctx_kernel(
    const float* __restrict__ wsoft, const float* __restrict__ out1,
    float* __restrict__ ctx)
{
  int b = blockIdx.x >> 3, h = blockIdx.x & 7;
  int d = threadIdx.x;  // 256
  float acc = 0.f;
  for (int l = 0; l < LL; ++l) {
    float w = wsoft[((size_t)l * BB + b) * NHH + h];
    acc += w * out1[((size_t)l * BB + b) * HH + d];
  }
  ctx[(size_t)b * (NHH * HH) + h * HH + d] = acc;
}

// ---------------------------------------------------------------------------
// final MLP: z = selu([ctx, hT] @ Wf0.T + bf0); logits = z @ Wf1.T + bf1;
// out = log_softmax(logits)
// ---------------------------------------------------------------------------
__global__ __launch_bounds__(512) void final_kernel(
    const float* __restrict__ ctx, const float* __restrict__ hT,
    const float* __restrict__ Wf0,   // [168][2304]
    const float* __restrict__ bf0,
    const float* __restrict__ Wf1,   // [100][168]
    const float* __restrict__ bf1,
    float* __restrict__ outp)        // [B][100]
{
  int b = blockIdx.x;
  int tid = threadIdx.x;
  int wave = tid >> 6, lane = tid & 63;
  __shared__ float4 xs4[CLSIN / 4];
  __shared__ float zs[F1];
  __shared__ float ls[ETA];
  float* xs = (float*)xs4;
  for (int i = tid; i < NHH * HH; i += 512) xs[i] = ctx[(size_t)b * (NHH * HH) + i];
  if (tid < HH) xs[NHH * HH + tid] = hT[(size_t)b * HH + tid];
  __syncthreads();
  for (int r = wave; r < F1; r += 8) {
    const float4* wp = (const float4*)(Wf0 + (size_t)r * CLSIN);
    float acc = 0.f;
    #pragma unroll
    for (int i = 0; i < CLSIN / 4 / 64; ++i) {  // 9
      float4 w = wp[lane + 64 * i];
      float4 x = xs4[lane + 64 * i];
      acc += w.x * x.x + w.y * x.y + w.z * x.z + w.w * x.w;
    }
    #pragma unroll
    for (int off = 32; off > 0; off >>= 1) acc += __shfl_xor(acc, off, 64);
    if (lane == 0) {
      float x = acc + bf0[r];
      const float alpha = 1.6732632423543772f, scale = 1.0507009873554805f;
      zs[r] = scale * (x > 0.f ? x : alpha * (__expf(x) - 1.f));
    }
  }
  __syncthreads();
  for (int r = wave; r < ETA; r += 8) {
    float acc = 0.f;
    for (int k = lane; k < F1; k += 64) acc += Wf1[r * F1 + k] * zs[k];
    #pragma unroll
    for (int off = 32; off > 0; off >>= 1) acc += __shfl_xor(acc, off, 64);
    if (lane == 0) ls[r] = acc + bf1[r];
  }
  __syncthreads();
  if (wave == 0) {
    float v0 = (lane < ETA) ? ls[lane] : -1e30f;
    float v1 = (lane + 64 < ETA) ? ls[lane + 64] : -1e30f;
    float m = fmaxf(v0, v1);
    #pragma unroll
    for (int off = 32; off > 0; off >>= 1) m = fmaxf(m, __shfl_xor(m, off, 64));
    float s = __expf(v0 - m) + __expf(v1 - m);
    #pragma unroll
    for (int off = 32; off > 0; off >>= 1) s += __shfl_xor(s, off, 64);
    float lse = m + __logf(s);
    if (lane < ETA) outp[(size_t)b * ETA + lane] = v0 - lse;
    if (lane + 64 < ETA) outp[(size_t)b * ETA + lane + 64] = v1 - lse;
  }
}

extern "C" void kernel_launch(void* const* d_in, const int* in_sizes, int n_in,
                              void* d_out, int out_size, void* d_ws, size_t ws_size,
                              hipStream_t stream) {
  const int*   node  = (const int*)d_in[0];
  const float* ts    = (const float*)d_in[1];
  const int*   slen  = (const int*)d_in[2];
  const float* table = (const float*)d_in[3];
  const float* Wih0  = (const float*)d_in[4];
  const float* Whh0  = (const float*)d_in[5];
  const float* bih0  = (const float*)d_in[6];
  const float* bhh0  = (const float*)d_in[7];
  const float* Wih1  = (const float*)d_in[8];
  const float* Whh1  = (const float*)d_in[9];
  const float* bih1  = (const float*)d_in[10];
  const float* bhh1  = (const float*)d_in[11];
  const float* Wa0   = (const float*)d_in[12];
  const float* ba0   = (const float*)d_in[13];
  const float* Wa1   = (const float*)d_in[14];
  const float* ba1   = (const float*)d_in[15];
  const float* Wf0   = (const float*)d_in[16];
  const float* bf0   = (const float*)d_in[17];
  const float* Wf1   = (const float*)d_in[18];
  const float* bf1   = (const float*)d_in[19];

  char* ws = (char*)d_ws;
  size_t off = 0;
  auto alloc = [&](size_t n) { void* p = (void*)(ws + off); off += (n + 255) & ~(size_t)255; return p; };

  half2v* e_h2 = (half2v*)alloc((size_t)LL * BB * 64 * 4);
  float* U     = (float*)alloc((size_t)LL * BB * EE * 4);
  float* V     = (float*)alloc((size_t)LL * BB * EE * 4);
  float* gi    = (float*)alloc((size_t)LL * BB * G3 * 4);   // reused for both layers
  float* out0  = (float*)alloc((size_t)LL * BB * HH * 4);
  float* out1  = (float*)alloc((size_t)LL * BB * HH * 4);
  float* hTb   = (float*)alloc((size_t)BB * HH * 4);
  float* wpre  = (float*)alloc((size_t)LL * BB * NHH * 4);
  float* wsoft = (float*)alloc((size_t)LL * BB * NHH * 4);
  float* ctxb  = (float*)alloc((size_t)BB * NHH * HH * 4);
  half_t* Wa0Ta = (half_t*)alloc((size_t)128 * 128 * 2);
  half_t* Wa0Tb = (half_t*)alloc((size_t)128 * 128 * 2);
  half2v* Wih0T2 = (half2v*)alloc((size_t)65 * 768 * 4);
  half2v* Wih1T2 = (half2v*)alloc((size_t)128 * 768 * 4);
  half_t* Whh0h = (half_t*)alloc((size_t)G3 * HH * 2);
  half_t* Whh1h = (half_t*)alloc((size_t)G3 * HH * 2);
  if (off > ws_size) return;  // workspace too small: fail visibly

  const int prep_total = 16384 + 16384 + 65 * 768 + 128 * 768 + 196608 + 196608;
  prep_kernel<<<(prep_total + 255) / 256, 256, 0, stream>>>(
      Wa0, Wih0, Wih1, Whh0, Whh1, Wa0Ta, Wa0Tb, Wih0T2, Wih1T2, Whh0h, Whh1h);
  embed_uv_kernel<<<LL * BB, 128, 0, stream>>>(node, table, Wa0Ta, Wa0Tb, ba0, e_h2, U, V);
  attn_w_kernel<<<(LL / 4) * BB, 128, 0, stream>>>(U, V, Wa1, ba1, wpre);
  attn_softmax_kernel<<<BB * NHH, 128, 0, stream>>>(wpre, slen, wsoft);
  gi0_kernel<<<LL * BB / 8, 256, 0, stream>>>(e_h2, ts, Wih0T2, bih0, gi);
  gru_scan_kernel<<<BB, 512, 0, stream>>>(Whh0h, bhh0, gi, slen, out0, hTb);
  gi1_kernel<<<LL * BB / 8, 256, 0, stream>>>(out0, Wih1T2, bih1, gi);
  gru_scan_kernel<<<BB, 512, 0, stream>>>(Whh1h, bhh1, gi, slen, out1, hTb);
  ctx_kernel<<<BB * NHH, 256, 0, stream>>>(wsoft, out1, ctxb);
  final_kernel<<<BB, 512, 0, stream>>>(ctxb, hTb, Wf0, bf0, Wf1, bf1, (float*)d_out);
}

// Round 4
// 590.900 us; speedup vs baseline: 1.3919x; 1.0030x over previous
//
#include <hip/hip_runtime.h>
#include <hip/hip_bf16.h>

#define LL 128
#define BB 32
#define EE 128
#define HH 256
#define NHH 8
#define G3 768   // 3*H
#define IN0 130
#define ETA 100
#define F1 168
#define CLSIN 2304  // 8*256 + 256

typedef _Float16 half_t;
typedef __attribute__((ext_vector_type(2))) _Float16 half2v;

#if defined(__has_builtin)
#if __has_builtin(__builtin_amdgcn_fdot2)
#define HAVE_FDOT2 1
#endif
#endif

__device__ __forceinline__ float fdot2f(half2v a, half2v b, float c) {
#ifdef HAVE_FDOT2
  return __builtin_amdgcn_fdot2(a, b, c, false);
#else
  return c + (float)a.x * (float)b.x + (float)a.y * (float)b.y;
#endif
}
__device__ __forceinline__ float fdot2u(unsigned int a, unsigned int b, float c) {
  return fdot2f(__builtin_bit_cast(half2v, a), __builtin_bit_cast(half2v, b), c);
}

// LDS-only barrier: skip the compiler's vmcnt(0) drain (no cross-thread
// global-memory dependencies at our barriers).
#define BARRIER_LDS() __asm__ volatile("s_waitcnt lgkmcnt(0)\n\ts_barrier" ::: "memory")

__device__ __forceinline__ float sigmoidf_(float x) { return 1.0f / (1.0f + __expf(-x)); }
__device__ __forceinline__ float tanhf_(float x) { return 1.0f - 2.0f / (__expf(2.0f * x) + 1.0f); }

// ---------------------------------------------------------------------------
// prep: weight repack fp32 -> f16 (weights ~N(0,0.05^2): f16 rel err 5e-4)
// ---------------------------------------------------------------------------
__global__ void prep_kernel(
    const float* __restrict__ Wa0, const float* __restrict__ Wih0,
    const float* __restrict__ Wih1, const float* __restrict__ Whh0,
    const float* __restrict__ Whh1,
    half_t* __restrict__ Wa0Ta, half_t* __restrict__ Wa0Tb,
    half2v* __restrict__ Wih0T2, half2v* __restrict__ Wih1T2,
    half_t* __restrict__ Whh0h, half_t* __restrict__ Whh1h)
{
  int idx = blockIdx.x * blockDim.x + threadIdx.x;
  const int n1 = 16384, n2 = 16384, n3 = 65 * 768, n4 = 128 * 768, n5 = 196608;
  if (idx < n1) {
    int d = idx >> 7, k = idx & 127;
    Wa0Ta[idx] = (half_t)Wa0[k * 256 + d];
  } else if ((idx -= n1) < n2) {
    int d = idx >> 7, k = idx & 127;
    Wa0Tb[idx] = (half_t)Wa0[k * 256 + 128 + d];
  } else if ((idx -= n2) < n3) {
    int d2 = idx / 768, r = idx % 768;
    half2v w; w.x = (half_t)Wih0[r * IN0 + 2 * d2]; w.y = (half_t)Wih0[r * IN0 + 2 * d2 + 1];
    Wih0T2[idx] = w;
  } else if ((idx -= n3) < n4) {
    int d2 = idx / 768, r = idx % 768;
    half2v w; w.x = (half_t)Wih1[r * HH + 2 * d2]; w.y = (half_t)Wih1[r * HH + 2 * d2 + 1];
    Wih1T2[idx] = w;
  } else if ((idx -= n4) < n5) {
    Whh0h[idx] = (half_t)Whh0[idx];
  } else if ((idx -= n5) < n5) {
    Whh1h[idx] = (half_t)Whh1[idx];
  }
}

// ---------------------------------------------------------------------------
// embed gather + U/V factors of the pairwise attention
// ---------------------------------------------------------------------------
__global__ void embed_uv_kernel(
    const int* __restrict__ node,             // [L*B]
    const float* __restrict__ table,          // [20001][128]
    const half_t* __restrict__ Wa0Ta,         // [128 d][128 k]
    const half_t* __restrict__ Wa0Tb,
    const float* __restrict__ ba0,            // [128]
    half2v* __restrict__ e_h2,                // [L*B][64]
    float* __restrict__ U,
    float* __restrict__ V)
{
  int lb = blockIdx.x;
  int k = threadIdx.x;  // 128
  __shared__ float es[EE];
  int n = node[lb];
  float ev = table[(size_t)n * EE + k];
  es[k] = ev;
  __syncthreads();
  if (k < 64) {
    half2v p; p.x = (half_t)es[2 * k]; p.y = (half_t)es[2 * k + 1];
    e_h2[(size_t)lb * 64 + k] = p;
  }
  float u = 0.f, v = ba0[k];
  #pragma unroll 8
  for (int d = 0; d < EE; ++d) {
    float x = es[d];
    u += (float)Wa0Ta[d * EE + k] * x;
    v += (float)Wa0Tb[d * EE + k] * x;
  }
  U[(size_t)lb * EE + k] = u;
  V[(size_t)lb * EE + k] = v;
}

// ---------------------------------------------------------------------------
// w_pre[i,b,h] = sum_j sum_k Wa1[h,k] * relu(U[j,b,k]+V[i,b,k]) + L*ba1[h]
// ---------------------------------------------------------------------------
__global__ __launch_bounds__(128) void attn_w_kernel(
    const float* __restrict__ U, const float* __restrict__ V,
    const float* __restrict__ Wa1,  // [8][128]
    const float* __restrict__ ba1,  // [8]
    float* __restrict__ wpre)       // [L][B][8]
{
  int ig = blockIdx.x >> 5;
  int b = blockIdx.x & 31;
  int i0 = ig * 4;
  int k = threadIdx.x;  // 128
  float vk[4];
  #pragma unroll
  for (int ii = 0; ii < 4; ++ii) vk[ii] = V[((size_t)(i0 + ii) * BB + b) * EE + k];
  float wa[NHH], acc[4][NHH];
  #pragma unroll
  for (int h = 0; h < NHH; ++h) wa[h] = Wa1[h * EE + k];
  #pragma unroll
  for (int ii = 0; ii < 4; ++ii)
    #pragma unroll
    for (int h = 0; h < NHH; ++h) acc[ii][h] = 0.f;
  for (int j = 0; j < LL; ++j) {
    float u = U[((size_t)j * BB + b) * EE + k];
    #pragma unroll
    for (int ii = 0; ii < 4; ++ii) {
      float tv = fmaxf(u + vk[ii], 0.f);
      #pragma unroll
      for (int h = 0; h < NHH; ++h) acc[ii][h] += wa[h] * tv;
    }
  }
  __shared__ float part[2][32];
  int wave = k >> 6, lane = k & 63;
  #pragma unroll
  for (int ii = 0; ii < 4; ++ii)
    #pragma unroll
    for (int h = 0; h < NHH; ++h) {
      float a = acc[ii][h];
      #pragma unroll
      for (int off = 32; off > 0; off >>= 1) a += __shfl_xor(a, off, 64);
      if (lane == 0) part[wave][ii * 8 + h] = a;
    }
  __syncthreads();
  if (k < 32) {
    int ii = k >> 3, h = k & 7;
    float w = part[0][k] + part[1][k] + (float)LL * ba1[h];
    wpre[((size_t)(i0 + ii) * BB + b) * NHH + h] = w;
  }
}

// softmax over l of (w * mask): masked entries become 0 and STAY in the softmax
__global__ void attn_softmax_kernel(
    const float* __restrict__ wpre, const int* __restrict__ slen,
    float* __restrict__ wsoft)
{
  int b = blockIdx.x >> 3;
  int h = blockIdx.x & 7;
  int l = threadIdx.x;  // 128
  int len = slen[b];
  float x = wpre[((size_t)l * BB + b) * NHH + h];
  float xv = (l < len) ? x : 0.f;
  float m = xv;
  #pragma unroll
  for (int off = 32; off > 0; off >>= 1) m = fmaxf(m, __shfl_xor(m, off, 64));
  __shared__ float sm[2], ss[2];
  int wave = l >> 6;
  if ((l & 63) == 0) sm[wave] = m;
  __syncthreads();
  m = fmaxf(sm[0], sm[1]);
  float e = __expf(xv - m);
  float s = e;
  #pragma unroll
  for (int off = 32; off > 0; off >>= 1) s += __shfl_xor(s, off, 64);
  if ((l & 63) == 0) ss[wave] = s;
  __syncthreads();
  s = ss[0] + ss[1];
  wsoft[((size_t)l * BB + b) * NHH + h] = e / s;
}

// ---------------------------------------------------------------------------
// gi0: [e, ts] @ Wih0.T + bih0, 8 lb per block, v_dot2 on packed pairs
// ---------------------------------------------------------------------------
__global__ __launch_bounds__(256) void gi0_kernel(
    const half2v* __restrict__ e_h2, const float* __restrict__ ts,
    const half2v* __restrict__ W2,   // [65][768]
    const float* __restrict__ bih,
    float* __restrict__ gi)
{
  int lb0 = blockIdx.x * 8;
  int tid = threadIdx.x;  // 256
  __shared__ half2v xs2[8][66];
  for (int idx = tid; idx < 512; idx += 256) {
    int q = idx >> 6, d2 = idx & 63;
    xs2[q][d2] = e_h2[(size_t)(lb0 + q) * 64 + d2];
  }
  if (tid < 8) {
    half2v t2; t2.x = (half_t)ts[(lb0 + tid) * 2]; t2.y = (half_t)ts[(lb0 + tid) * 2 + 1];
    xs2[tid][64] = t2;
  }
  __syncthreads();
  float acc[8][3];
  #pragma unroll
  for (int q = 0; q < 8; ++q) { acc[q][0] = 0.f; acc[q][1] = 0.f; acc[q][2] = 0.f; }
  for (int d2 = 0; d2 < 65; ++d2) {
    half2v w0 = W2[d2 * 768 + tid];
    half2v w1 = W2[d2 * 768 + 256 + tid];
    half2v w2 = W2[d2 * 768 + 512 + tid];
    #pragma unroll
    for (int q = 0; q < 8; ++q) {
      half2v x = xs2[q][d2];
      acc[q][0] = fdot2f(w0, x, acc[q][0]);
      acc[q][1] = fdot2f(w1, x, acc[q][1]);
      acc[q][2] = fdot2f(w2, x, acc[q][2]);
    }
  }
  float b0 = bih[tid], b1 = bih[256 + tid], b2 = bih[512 + tid];
  #pragma unroll
  for (int q = 0; q < 8; ++q) {
    float* gp = gi + (size_t)(lb0 + q) * G3;
    gp[tid] = acc[q][0] + b0; gp[256 + tid] = acc[q][1] + b1; gp[512 + tid] = acc[q][2] + b2;
  }
}

// ---------------------------------------------------------------------------
// gi1: out0 @ Wih1.T + bih1, 8 lb per block
// ---------------------------------------------------------------------------
__global__ __launch_bounds__(256) void gi1_kernel(
    const float* __restrict__ out0,  // [L*B][256]
    const half2v* __restrict__ W2,   // [128][768]
    const float* __restrict__ bih,
    float* __restrict__ gi)
{
  int lb0 = blockIdx.x * 8;
  int tid = threadIdx.x;  // 256
  __shared__ half2v xs2[8][128];
  for (int idx = tid; idx < 1024; idx += 256) {
    int q = idx >> 7, d2 = idx & 127;
    float2 v = ((const float2*)(out0 + (size_t)(lb0 + q) * HH))[d2];
    half2v x; x.x = (half_t)v.x; x.y = (half_t)v.y;
    xs2[q][d2] = x;
  }
  __syncthreads();
  float acc[8][3];
  #pragma unroll
  for (int q = 0; q < 8; ++q) { acc[q][0] = 0.f; acc[q][1] = 0.f; acc[q][2] = 0.f; }
  for (int d2 = 0; d2 < 128; ++d2) {
    half2v w0 = W2[d2 * 768 + tid];
    half2v w1 = W2[d2 * 768 + 256 + tid];
    half2v w2 = W2[d2 * 768 + 512 + tid];
    #pragma unroll
    for (int q = 0; q < 8; ++q) {
      half2v x = xs2[q][d2];
      acc[q][0] = fdot2f(w0, x, acc[q][0]);
      acc[q][1] = fdot2f(w1, x, acc[q][1]);
      acc[q][2] = fdot2f(w2, x, acc[q][2]);
    }
  }
  float b0 = bih[tid], b1 = bih[256 + tid], b2 = bih[512 + tid];
  #pragma unroll
  for (int q = 0; q < 8; ++q) {
    float* gp = gi + (size_t)(lb0 + q) * G3;
    gp[tid] = acc[q][0] + b0; gp[256 + tid] = acc[q][1] + b1; gp[512 + tid] = acc[q][2] + b2;
  }
}

// ---------------------------------------------------------------------------
// GRU scan: one block per batch element. Thread (g = tid>>2, s = tid&3)
// holds rows 6g..6g+5 of Whh restricted to k-slice [64s, 64s+64) in 192
// pinned VGPRs (asm "+v" blocks rematerialization of the loads).
// LDS: h in 4 padded chunks (conflict-free b128 reads), partials stride-5
// (5*tid coprime 32 -> conflict-free phase-2 reads).
// ---------------------------------------------------------------------------
__global__ __launch_bounds__(512, 2) void gru_scan_kernel(
    const half_t* __restrict__ Whhh,         // [768][256] f16
    const float* __restrict__ bhh,           // [768]
    const float* __restrict__ gi,            // [L][B][768]
    const int* __restrict__ slen,            // [B]
    float* __restrict__ out,                 // [L][B][256]
    float* __restrict__ hT)                  // [B][256]
{
  const int b = blockIdx.x;
  const int tid = threadIdx.x;
  const int s = tid & 3;
  const int g = tid >> 2;
  __shared__ __align__(16) uint4 h4[4 * 9];  // 4 chunks x (8 data + 1 pad) float4
  __shared__ float p5[768 * 5];

  unsigned int wRegU[192];
  #pragma unroll
  for (int r = 0; r < 6; ++r) {
    const uint4* wp = (const uint4*)(Whhh + (size_t)(6 * g + r) * HH + 64 * s);
    #pragma unroll
    for (int j = 0; j < 8; ++j) {
      uint4 v = wp[j];
      wRegU[r * 32 + 4 * j + 0] = v.x; wRegU[r * 32 + 4 * j + 1] = v.y;
      wRegU[r * 32 + 4 * j + 2] = v.z; wRegU[r * 32 + 4 * j + 3] = v.w;
    }
  }
  #pragma unroll
  for (int i = 0; i < 192; ++i) __asm__ volatile("" : "+v"(wRegU[i]));

  const int len = slen[b];
  float bhr = 0.f, bhz = 0.f, bhn = 0.f, hold = 0.f;
  if (tid < HH) {
    bhr = bhh[tid]; bhz = bhh[HH + tid]; bhn = bhh[2 * HH + tid];
  }
  if (tid < 36) { uint4 z; z.x = z.y = z.z = z.w = 0u; h4[tid] = z; }
  __syncthreads();

  const float* gib = gi + (size_t)b * G3;
  float* outb = out + (size_t)b * HH;

  #pragma unroll 1
  for (int t = 0; t < LL; ++t) {
    float g0 = 0.f, g1 = 0.f, g2 = 0.f;
    if (tid < HH) {
      const float* gp = gib + (size_t)t * (BB * G3);
      g0 = gp[tid]; g1 = gp[HH + tid]; g2 = gp[2 * HH + tid];
    }
    float acc[6] = {0.f, 0.f, 0.f, 0.f, 0.f, 0.f};
    #pragma unroll
    for (int c = 0; c < 4; ++c) {
      uint4 ha = h4[s * 9 + 2 * c];
      uint4 hb = h4[s * 9 + 2 * c + 1];
      unsigned int hu[8] = {ha.x, ha.y, ha.z, ha.w, hb.x, hb.y, hb.z, hb.w};
      #pragma unroll
      for (int r = 0; r < 6; ++r) {
        #pragma unroll
        for (int i = 0; i < 8; ++i)
          acc[r] = fdot2u(wRegU[r * 32 + 8 * c + i], hu[i], acc[r]);
      }
    }
    #pragma unroll
    for (int r = 0; r < 6; ++r)
      p5[(6 * g + r) * 5 + s] = acc[r];
    BARRIER_LDS();
    if (tid < HH) {
      int b0 = tid * 5, b1 = (HH + tid) * 5, b2 = (2 * HH + tid) * 5;
      float srz = (p5[b0] + p5[b0 + 1]) + (p5[b0 + 2] + p5[b0 + 3]);
      float sz  = (p5[b1] + p5[b1 + 1]) + (p5[b1 + 2] + p5[b1 + 3]);
      float sn  = (p5[b2] + p5[b2 + 1]) + (p5[b2 + 2] + p5[b2 + 3]);
      float r_ = sigmoidf_(g0 + srz + bhr);
      float z_ = sigmoidf_(g1 + sz + bhz);
      float n_ = tanhf_(g2 + r_ * (sn + bhn));
      float hnew = (1.f - z_) * n_ + z_ * hold;
      bool valid = t < len;
      hold = valid ? hnew : hold;
      ((half_t*)(h4 + (tid >> 6) * 9))[tid & 63] = (half_t)hold;
      outb[(size_t)t * (BB * HH) + tid] = valid ? hnew : 0.f;
    }
    BARRIER_LDS();
  }
  if (tid < HH) hT[(size_t)b * HH + tid] = hold;
}

// ---------------------------------------------------------------------------
// ctx[b, h*256+d] = sum_l wsoft[l,b,h] * out1[l,b,d]
// ---------------------------------------------------------------------------
__global__ void ctx_kernel(
    const float* __restrict__ wsoft, const float* __restrict__ out1,
    float* __restrict__ ctx)
{
  int b = blockIdx.x >> 3, h = blockIdx.x & 7;
  int d = threadIdx.x;  // 256
  float acc = 0.f;
  for (int l = 0; l < LL; ++l) {
    float w = wsoft[((size_t)l * BB + b) * NHH + h];
    acc += w * out1[((size_t)l * BB + b) * HH + d];
  }
  ctx[(size_t)b * (NHH * HH) + h * HH + d] = acc;
}

// ---------------------------------------------------------------------------
// final MLP: z = selu([ctx, hT] @ Wf0.T + bf0); logits = z @ Wf1.T + bf1;
// out = log_softmax(logits)
// ---------------------------------------------------------------------------
__global__ __launch_bounds__(512) void final_kernel(
    const float* __restrict__ ctx, const float* __restrict__ hT,
    const float* __restrict__ Wf0,   // [168][2304]
    const float* __restrict__ bf0,
    const float* __restrict__ Wf1,   // [100][168]
    const float* __restrict__ bf1,
    float* __restrict__ outp)        // [B][100]
{
  int b = blockIdx.x;
  int tid = threadIdx.x;
  int wave = tid >> 6, lane = tid & 63;
  __shared__ float4 xs4[CLSIN / 4];
  __shared__ float zs[F1];
  __shared__ float ls[ETA];
  float* xs = (float*)xs4;
  for (int i = tid; i < NHH * HH; i += 512) xs[i] = ctx[(size_t)b * (NHH * HH) + i];
  if (tid < HH) xs[NHH * HH + tid] = hT[(size_t)b * HH + tid];
  __syncthreads();
  for (int r = wave; r < F1; r += 8) {
    const float4* wp = (const float4*)(Wf0 + (size_t)r * CLSIN);
    float acc = 0.f;
    #pragma unroll
    for (int i = 0; i < CLSIN / 4 / 64; ++i) {  // 9
      float4 w = wp[lane + 64 * i];
      float4 x = xs4[lane + 64 * i];
      acc += w.x * x.x + w.y * x.y + w.z * x.z + w.w * x.w;
    }
    #pragma unroll
    for (int off = 32; off > 0; off >>= 1) acc += __shfl_xor(acc, off, 64);
    if (lane == 0) {
      float x = acc + bf0[r];
      const float alpha = 1.6732632423543772f, scale = 1.0507009873554805f;
      zs[r] = scale * (x > 0.f ? x : alpha * (__expf(x) - 1.f));
    }
  }
  __syncthreads();
  for (int r = wave; r < ETA; r += 8) {
    float acc = 0.f;
    for (int k = lane; k < F1; k += 64) acc += Wf1[r * F1 + k] * zs[k];
    #pragma unroll
    for (int off = 32; off > 0; off >>= 1) acc += __shfl_xor(acc, off, 64);
    if (lane == 0) ls[r] = acc + bf1[r];
  }
  __syncthreads();
  if (wave == 0) {
    float v0 = (lane < ETA) ? ls[lane] : -1e30f;
    float v1 = (lane + 64 < ETA) ? ls[lane + 64] : -1e30f;
    float m = fmaxf(v0, v1);
    #pragma unroll
    for (int off = 32; off > 0; off >>= 1) m = fmaxf(m, __shfl_xor(m, off, 64));
    float s = __expf(v0 - m) + __expf(v1 - m);
    #pragma unroll
    for (int off = 32; off > 0; off >>= 1) s += __shfl_xor(s, off, 64);
    float lse = m + __logf(s);
    if (lane < ETA) outp[(size_t)b * ETA + lane] = v0 - lse;
    if (lane + 64 < ETA) outp[(size_t)b * ETA + lane + 64] = v1 - lse;
  }
}

extern "C" void kernel_launch(void* const* d_in, const int* in_sizes, int n_in,
                              void* d_out, int out_size, void* d_ws, size_t ws_size,
                              hipStream_t stream) {
  const int*   node  = (const int*)d_in[0];
  const float* ts    = (const float*)d_in[1];
  const int*   slen  = (const int*)d_in[2];
  const float* table = (const float*)d_in[3];
  const float* Wih0  = (const float*)d_in[4];
  const float* Whh0  = (const float*)d_in[5];
  const float* bih0  = (const float*)d_in[6];
  const float* bhh0  = (const float*)d_in[7];
  const float* Wih1  = (const float*)d_in[8];
  const float* Whh1  = (const float*)d_in[9];
  const float* bih1  = (const float*)d_in[10];
  const float* bhh1  = (const float*)d_in[11];
  const float* Wa0   = (const float*)d_in[12];
  const float* ba0   = (const float*)d_in[13];
  const float* Wa1   = (const float*)d_in[14];
  const float* ba1   = (const float*)d_in[15];
  const float* Wf0   = (const float*)d_in[16];
  const float* bf0   = (const float*)d_in[17];
  const float* Wf1   = (const float*)d_in[18];
  const float* bf1   = (const float*)d_in[19];

  char* ws = (char*)d_ws;
  size_t off = 0;
  auto alloc = [&](size_t n) { void* p = (void*)(ws + off); off += (n + 255) & ~(size_t)255; return p; };

  half2v* e_h2 = (half2v*)alloc((size_t)LL * BB * 64 * 4);
  float* U     = (float*)alloc((size_t)LL * BB * EE * 4);
  float* V     = (float*)alloc((size_t)LL * BB * EE * 4);
  float* gi    = (float*)alloc((size_t)LL * BB * G3 * 4);   // reused for both layers
  float* out0  = (float*)alloc((size_t)LL * BB * HH * 4);
  float* out1  = (float*)alloc((size_t)LL * BB * HH * 4);
  float* hTb   = (float*)alloc((size_t)BB * HH * 4);
  float* wpre  = (float*)alloc((size_t)LL * BB * NHH * 4);
  float* wsoft = (float*)alloc((size_t)LL * BB * NHH * 4);
  float* ctxb  = (float*)alloc((size_t)BB * NHH * HH * 4);
  half_t* Wa0Ta = (half_t*)alloc((size_t)128 * 128 * 2);
  half_t* Wa0Tb = (half_t*)alloc((size_t)128 * 128 * 2);
  half2v* Wih0T2 = (half2v*)alloc((size_t)65 * 768 * 4);
  half2v* Wih1T2 = (half2v*)alloc((size_t)128 * 768 * 4);
  half_t* Whh0h = (half_t*)alloc((size_t)G3 * HH * 2);
  half_t* Whh1h = (half_t*)alloc((size_t)G3 * HH * 2);
  if (off > ws_size) return;  // workspace too small: fail visibly

  const int prep_total = 16384 + 16384 + 65 * 768 + 128 * 768 + 196608 + 196608;
  prep_kernel<<<(prep_total + 255) / 256, 256, 0, stream>>>(
      Wa0, Wih0, Wih1, Whh0, Whh1, Wa0Ta, Wa0Tb, Wih0T2, Wih1T2, Whh0h, Whh1h);
  embed_uv_kernel<<<LL * BB, 128, 0, stream>>>(node, table, Wa0Ta, Wa0Tb, ba0, e_h2, U, V);
  attn_w_kernel<<<(LL / 4) * BB, 128, 0, stream>>>(U, V, Wa1, ba1, wpre);
  attn_softmax_kernel<<<BB * NHH, 128, 0, stream>>>(wpre, slen, wsoft);
  gi0_kernel<<<LL * BB / 8, 256, 0, stream>>>(e_h2, ts, Wih0T2, bih0, gi);
  gru_scan_kernel<<<BB, 512, 0, stream>>>(Whh0h, bhh0, gi, slen, out0, hTb);
  gi1_kernel<<<LL * BB / 8, 256, 0, stream>>>(out0, Wih1T2, bih1, gi);
  gru_scan_kernel<<<BB, 512, 0, stream>>>(Whh1h, bhh1, gi, slen, out1, hTb);
  ctx_kernel<<<BB * NHH, 256, 0, stream>>>(wsoft, out1, ctxb);
  final_kernel<<<BB, 512, 0, stream>>>(ctxb, hTb, Wf0, bf0, Wf1, bf1, (float*)d_out);
}

// Round 5
// 585.788 us; speedup vs baseline: 1.4041x; 1.0087x over previous
//
#include <hip/hip_runtime.h>
#include <hip/hip_bf16.h>

#define LL 128
#define BB 32
#define EE 128
#define HH 256
#define NHH 8
#define G3 768   // 3*H
#define IN0 130
#define ETA 100
#define F1 168
#define CLSIN 2304  // 8*256 + 256

typedef _Float16 half_t;
typedef __attribute__((ext_vector_type(2))) _Float16 half2v;
typedef __attribute__((ext_vector_type(16))) unsigned int uint16v;

#if defined(__has_builtin)
#if __has_builtin(__builtin_amdgcn_fdot2)
#define HAVE_FDOT2 1
#endif
#endif

__device__ __forceinline__ float fdot2f(half2v a, half2v b, float c) {
#ifdef HAVE_FDOT2
  return __builtin_amdgcn_fdot2(a, b, c, false);
#else
  return c + (float)a.x * (float)b.x + (float)a.y * (float)b.y;
#endif
}
__device__ __forceinline__ float fdot2u(unsigned int a, unsigned int b, float c) {
  return fdot2f(__builtin_bit_cast(half2v, a), __builtin_bit_cast(half2v, b), c);
}

// LDS-only barrier: skip the compiler's vmcnt(0) drain (no cross-thread
// global-memory dependencies at our barriers).
#define BARRIER_LDS() __asm__ volatile("s_waitcnt lgkmcnt(0)\n\ts_barrier" ::: "memory")

__device__ __forceinline__ float sigmoidf_(float x) { return 1.0f / (1.0f + __expf(-x)); }
__device__ __forceinline__ float tanhf_(float x) { return 1.0f - 2.0f / (__expf(2.0f * x) + 1.0f); }

// ---------------------------------------------------------------------------
// prep: weight repack fp32 -> f16 (weights ~N(0,0.05^2): f16 rel err 5e-4)
// ---------------------------------------------------------------------------
__global__ void prep_kernel(
    const float* __restrict__ Wa0, const float* __restrict__ Wih0,
    const float* __restrict__ Wih1, const float* __restrict__ Whh0,
    const float* __restrict__ Whh1,
    half_t* __restrict__ Wa0Ta, half_t* __restrict__ Wa0Tb,
    half2v* __restrict__ Wih0T2, half2v* __restrict__ Wih1T2,
    half_t* __restrict__ Whh0h, half_t* __restrict__ Whh1h)
{
  int idx = blockIdx.x * blockDim.x + threadIdx.x;
  const int n1 = 16384, n2 = 16384, n3 = 65 * 768, n4 = 128 * 768, n5 = 196608;
  if (idx < n1) {
    int d = idx >> 7, k = idx & 127;
    Wa0Ta[idx] = (half_t)Wa0[k * 256 + d];
  } else if ((idx -= n1) < n2) {
    int d = idx >> 7, k = idx & 127;
    Wa0Tb[idx] = (half_t)Wa0[k * 256 + 128 + d];
  } else if ((idx -= n2) < n3) {
    int d2 = idx / 768, r = idx % 768;
    half2v w; w.x = (half_t)Wih0[r * IN0 + 2 * d2]; w.y = (half_t)Wih0[r * IN0 + 2 * d2 + 1];
    Wih0T2[idx] = w;
  } else if ((idx -= n3) < n4) {
    int d2 = idx / 768, r = idx % 768;
    half2v w; w.x = (half_t)Wih1[r * HH + 2 * d2]; w.y = (half_t)Wih1[r * HH + 2 * d2 + 1];
    Wih1T2[idx] = w;
  } else if ((idx -= n4) < n5) {
    Whh0h[idx] = (half_t)Whh0[idx];
  } else if ((idx -= n5) < n5) {
    Whh1h[idx] = (half_t)Whh1[idx];
  }
}

// ---------------------------------------------------------------------------
// embed gather + U/V factors of the pairwise attention
// ---------------------------------------------------------------------------
__global__ void embed_uv_kernel(
    const int* __restrict__ node,             // [L*B]
    const float* __restrict__ table,          // [20001][128]
    const half_t* __restrict__ Wa0Ta,         // [128 d][128 k]
    const half_t* __restrict__ Wa0Tb,
    const float* __restrict__ ba0,            // [128]
    half2v* __restrict__ e_h2,                // [L*B][64]
    float* __restrict__ U,
    float* __restrict__ V)
{
  int lb = blockIdx.x;
  int k = threadIdx.x;  // 128
  __shared__ float es[EE];
  int n = node[lb];
  float ev = table[(size_t)n * EE + k];
  es[k] = ev;
  __syncthreads();
  if (k < 64) {
    half2v p; p.x = (half_t)es[2 * k]; p.y = (half_t)es[2 * k + 1];
    e_h2[(size_t)lb * 64 + k] = p;
  }
  float u = 0.f, v = ba0[k];
  #pragma unroll 8
  for (int d = 0; d < EE; ++d) {
    float x = es[d];
    u += (float)Wa0Ta[d * EE + k] * x;
    v += (float)Wa0Tb[d * EE + k] * x;
  }
  U[(size_t)lb * EE + k] = u;
  V[(size_t)lb * EE + k] = v;
}

// ---------------------------------------------------------------------------
// w_pre[i,b,h] = sum_j sum_k Wa1[h,k] * relu(U[j,b,k]+V[i,b,k]) + L*ba1[h]
// ---------------------------------------------------------------------------
__global__ __launch_bounds__(128) void attn_w_kernel(
    const float* __restrict__ U, const float* __restrict__ V,
    const float* __restrict__ Wa1,  // [8][128]
    const float* __restrict__ ba1,  // [8]
    float* __restrict__ wpre)       // [L][B][8]
{
  int ig = blockIdx.x >> 5;
  int b = blockIdx.x & 31;
  int i0 = ig * 4;
  int k = threadIdx.x;  // 128
  float vk[4];
  #pragma unroll
  for (int ii = 0; ii < 4; ++ii) vk[ii] = V[((size_t)(i0 + ii) * BB + b) * EE + k];
  float wa[NHH], acc[4][NHH];
  #pragma unroll
  for (int h = 0; h < NHH; ++h) wa[h] = Wa1[h * EE + k];
  #pragma unroll
  for (int ii = 0; ii < 4; ++ii)
    #pragma unroll
    for (int h = 0; h < NHH; ++h) acc[ii][h] = 0.f;
  for (int j = 0; j < LL; ++j) {
    float u = U[((size_t)j * BB + b) * EE + k];
    #pragma unroll
    for (int ii = 0; ii < 4; ++ii) {
      float tv = fmaxf(u + vk[ii], 0.f);
      #pragma unroll
      for (int h = 0; h < NHH; ++h) acc[ii][h] += wa[h] * tv;
    }
  }
  __shared__ float part[2][32];
  int wave = k >> 6, lane = k & 63;
  #pragma unroll
  for (int ii = 0; ii < 4; ++ii)
    #pragma unroll
    for (int h = 0; h < NHH; ++h) {
      float a = acc[ii][h];
      #pragma unroll
      for (int off = 32; off > 0; off >>= 1) a += __shfl_xor(a, off, 64);
      if (lane == 0) part[wave][ii * 8 + h] = a;
    }
  __syncthreads();
  if (k < 32) {
    int ii = k >> 3, h = k & 7;
    float w = part[0][k] + part[1][k] + (float)LL * ba1[h];
    wpre[((size_t)(i0 + ii) * BB + b) * NHH + h] = w;
  }
}

// softmax over l of (w * mask): masked entries become 0 and STAY in the softmax
__global__ void attn_softmax_kernel(
    const float* __restrict__ wpre, const int* __restrict__ slen,
    float* __restrict__ wsoft)
{
  int b = blockIdx.x >> 3;
  int h = blockIdx.x & 7;
  int l = threadIdx.x;  // 128
  int len = slen[b];
  float x = wpre[((size_t)l * BB + b) * NHH + h];
  float xv = (l < len) ? x : 0.f;
  float m = xv;
  #pragma unroll
  for (int off = 32; off > 0; off >>= 1) m = fmaxf(m, __shfl_xor(m, off, 64));
  __shared__ float sm[2], ss[2];
  int wave = l >> 6;
  if ((l & 63) == 0) sm[wave] = m;
  __syncthreads();
  m = fmaxf(sm[0], sm[1]);
  float e = __expf(xv - m);
  float s = e;
  #pragma unroll
  for (int off = 32; off > 0; off >>= 1) s += __shfl_xor(s, off, 64);
  if ((l & 63) == 0) ss[wave] = s;
  __syncthreads();
  s = ss[0] + ss[1];
  wsoft[((size_t)l * BB + b) * NHH + h] = e / s;
}

// ---------------------------------------------------------------------------
// gi0: [e, ts] @ Wih0.T + bih0, 8 lb per block, v_dot2 on packed pairs
// ---------------------------------------------------------------------------
__global__ __launch_bounds__(256) void gi0_kernel(
    const half2v* __restrict__ e_h2, const float* __restrict__ ts,
    const half2v* __restrict__ W2,   // [65][768]
    const float* __restrict__ bih,
    float* __restrict__ gi)
{
  int lb0 = blockIdx.x * 8;
  int tid = threadIdx.x;  // 256
  __shared__ half2v xs2[8][66];
  for (int idx = tid; idx < 512; idx += 256) {
    int q = idx >> 6, d2 = idx & 63;
    xs2[q][d2] = e_h2[(size_t)(lb0 + q) * 64 + d2];
  }
  if (tid < 8) {
    half2v t2; t2.x = (half_t)ts[(lb0 + tid) * 2]; t2.y = (half_t)ts[(lb0 + tid) * 2 + 1];
    xs2[tid][64] = t2;
  }
  __syncthreads();
  float acc[8][3];
  #pragma unroll
  for (int q = 0; q < 8; ++q) { acc[q][0] = 0.f; acc[q][1] = 0.f; acc[q][2] = 0.f; }
  for (int d2 = 0; d2 < 65; ++d2) {
    half2v w0 = W2[d2 * 768 + tid];
    half2v w1 = W2[d2 * 768 + 256 + tid];
    half2v w2 = W2[d2 * 768 + 512 + tid];
    #pragma unroll
    for (int q = 0; q < 8; ++q) {
      half2v x = xs2[q][d2];
      acc[q][0] = fdot2f(w0, x, acc[q][0]);
      acc[q][1] = fdot2f(w1, x, acc[q][1]);
      acc[q][2] = fdot2f(w2, x, acc[q][2]);
    }
  }
  float b0 = bih[tid], b1 = bih[256 + tid], b2 = bih[512 + tid];
  #pragma unroll
  for (int q = 0; q < 8; ++q) {
    float* gp = gi + (size_t)(lb0 + q) * G3;
    gp[tid] = acc[q][0] + b0; gp[256 + tid] = acc[q][1] + b1; gp[512 + tid] = acc[q][2] + b2;
  }
}

// ---------------------------------------------------------------------------
// gi1: out0 @ Wih1.T + bih1, 8 lb per block
// ---------------------------------------------------------------------------
__global__ __launch_bounds__(256) void gi1_kernel(
    const float* __restrict__ out0,  // [L*B][256]
    const half2v* __restrict__ W2,   // [128][768]
    const float* __restrict__ bih,
    float* __restrict__ gi)
{
  int lb0 = blockIdx.x * 8;
  int tid = threadIdx.x;  // 256
  __shared__ half2v xs2[8][128];
  for (int idx = tid; idx < 1024; idx += 256) {
    int q = idx >> 7, d2 = idx & 127;
    float2 v = ((const float2*)(out0 + (size_t)(lb0 + q) * HH))[d2];
    half2v x; x.x = (half_t)v.x; x.y = (half_t)v.y;
    xs2[q][d2] = x;
  }
  __syncthreads();
  float acc[8][3];
  #pragma unroll
  for (int q = 0; q < 8; ++q) { acc[q][0] = 0.f; acc[q][1] = 0.f; acc[q][2] = 0.f; }
  for (int d2 = 0; d2 < 128; ++d2) {
    half2v w0 = W2[d2 * 768 + tid];
    half2v w1 = W2[d2 * 768 + 256 + tid];
    half2v w2 = W2[d2 * 768 + 512 + tid];
    #pragma unroll
    for (int q = 0; q < 8; ++q) {
      half2v x = xs2[q][d2];
      acc[q][0] = fdot2f(w0, x, acc[q][0]);
      acc[q][1] = fdot2f(w1, x, acc[q][1]);
      acc[q][2] = fdot2f(w2, x, acc[q][2]);
    }
  }
  float b0 = bih[tid], b1 = bih[256 + tid], b2 = bih[512 + tid];
  #pragma unroll
  for (int q = 0; q < 8; ++q) {
    float* gp = gi + (size_t)(lb0 + q) * G3;
    gp[tid] = acc[q][0] + b0; gp[256 + tid] = acc[q][1] + b1; gp[512 + tid] = acc[q][2] + b2;
  }
}

// ---------------------------------------------------------------------------
// GRU scan: one block per batch element. Thread (g = tid>>2, s = tid&3)
// holds rows 6g..6g+5 of Whh restricted to k-slice [64s, 64s+64) as
// 12 x uint16 ext-vectors = 192 VGPRs. A single asm with all 12 "+v"
// vector operands at the top of EVERY t-iteration forces true residency
// (spilling 12 vectors/iter is strictly worse for the allocator).
// ---------------------------------------------------------------------------
__global__ __launch_bounds__(512, 2) void gru_scan_kernel(
    const half_t* __restrict__ Whhh,         // [768][256] f16
    const float* __restrict__ bhh,           // [768]
    const float* __restrict__ gi,            // [L][B][768]
    const int* __restrict__ slen,            // [B]
    float* __restrict__ out,                 // [L][B][256]
    float* __restrict__ hT)                  // [B][256]
{
  const int b = blockIdx.x;
  const int tid = threadIdx.x;
  const int s = tid & 3;
  const int g = tid >> 2;
  __shared__ __align__(16) uint4 h4[4 * 9];  // 4 chunks x (8 data + 1 pad) float4
  __shared__ float p5[768 * 5];

  uint16v W[12];
  #pragma unroll
  for (int r = 0; r < 6; ++r) {
    const uint4* wp = (const uint4*)(Whhh + (size_t)(6 * g + r) * HH + 64 * s);
    #pragma unroll
    for (int j = 0; j < 8; ++j) {
      uint4 v = wp[j];
      int base = 4 * j;  // 0,4,...,28 — constant after unroll
      if (base < 16) {
        W[2 * r][base] = v.x; W[2 * r][base + 1] = v.y;
        W[2 * r][base + 2] = v.z; W[2 * r][base + 3] = v.w;
      } else {
        W[2 * r + 1][base - 16] = v.x; W[2 * r + 1][base - 15] = v.y;
        W[2 * r + 1][base - 14] = v.z; W[2 * r + 1][base - 13] = v.w;
      }
    }
  }

  const int len = slen[b];
  float bhr = 0.f, bhz = 0.f, bhn = 0.f, hold = 0.f;
  if (tid < HH) {
    bhr = bhh[tid]; bhz = bhh[HH + tid]; bhn = bhh[2 * HH + tid];
  }
  if (tid < 36) { uint4 z; z.x = z.y = z.z = z.w = 0u; h4[tid] = z; }
  __syncthreads();

  const float* gib = gi + (size_t)b * G3;
  float* outb = out + (size_t)b * HH;

  #pragma unroll 1
  for (int t = 0; t < LL; ++t) {
    // pin all 12 weight vectors live at every iteration boundary
    __asm__ volatile(""
        : "+v"(W[0]), "+v"(W[1]), "+v"(W[2]), "+v"(W[3]), "+v"(W[4]),
          "+v"(W[5]), "+v"(W[6]), "+v"(W[7]), "+v"(W[8]), "+v"(W[9]),
          "+v"(W[10]), "+v"(W[11]));
    float g0 = 0.f, g1 = 0.f, g2 = 0.f;
    if (tid < HH) {
      const float* gp = gib + (size_t)t * (BB * G3);
      g0 = gp[tid]; g1 = gp[HH + tid]; g2 = gp[2 * HH + tid];
    }
    float acc[6] = {0.f, 0.f, 0.f, 0.f, 0.f, 0.f};
    #pragma unroll
    for (int c = 0; c < 4; ++c) {
      uint4 ha = h4[s * 9 + 2 * c];
      uint4 hb = h4[s * 9 + 2 * c + 1];
      unsigned int hu[8] = {ha.x, ha.y, ha.z, ha.w, hb.x, hb.y, hb.z, hb.w};
      #pragma unroll
      for (int r = 0; r < 6; ++r) {
        #pragma unroll
        for (int i = 0; i < 8; ++i) {
          int idx = 8 * c + i;  // constant after unroll
          unsigned int wv = (idx < 16) ? W[2 * r][idx] : W[2 * r + 1][idx - 16];
          acc[r] = fdot2u(wv, hu[i], acc[r]);
        }
      }
    }
    #pragma unroll
    for (int r = 0; r < 6; ++r)
      p5[(6 * g + r) * 5 + s] = acc[r];
    BARRIER_LDS();
    if (tid < HH) {
      int b0 = tid * 5, b1 = (HH + tid) * 5, b2 = (2 * HH + tid) * 5;
      float srz = (p5[b0] + p5[b0 + 1]) + (p5[b0 + 2] + p5[b0 + 3]);
      float sz  = (p5[b1] + p5[b1 + 1]) + (p5[b1 + 2] + p5[b1 + 3]);
      float sn  = (p5[b2] + p5[b2 + 1]) + (p5[b2 + 2] + p5[b2 + 3]);
      float r_ = sigmoidf_(g0 + srz + bhr);
      float z_ = sigmoidf_(g1 + sz + bhz);
      float n_ = tanhf_(g2 + r_ * (sn + bhn));
      float hnew = (1.f - z_) * n_ + z_ * hold;
      bool valid = t < len;
      hold = valid ? hnew : hold;
      ((half_t*)(h4 + (tid >> 6) * 9))[tid & 63] = (half_t)hold;
      outb[(size_t)t * (BB * HH) + tid] = valid ? hnew : 0.f;
    }
    BARRIER_LDS();
  }
  if (tid < HH) hT[(size_t)b * HH + tid] = hold;
}

// ---------------------------------------------------------------------------
// ctx[b, h*256+d] = sum_l wsoft[l,b,h] * out1[l,b,d]
// ---------------------------------------------------------------------------
__global__ void ctx_kernel(
    const float* __restrict__ wsoft, const float* __restrict__ out1,
    float* __restrict__ ctx)
{
  int b = blockIdx.x >> 3, h = blockIdx.x & 7;
  int d = threadIdx.x;  // 256
  float acc = 0.f;
  for (int l = 0; l < LL; ++l) {
    float w = wsoft[((size_t)l * BB + b) * NHH + h];
    acc += w * out1[((size_t)l * BB + b) * HH + d];
  }
  ctx[(size_t)b * (NHH * HH) + h * HH + d] = acc;
}

// ---------------------------------------------------------------------------
// final MLP: z = selu([ctx, hT] @ Wf0.T + bf0); logits = z @ Wf1.T + bf1;
// out = log_softmax(logits)
// ---------------------------------------------------------------------------
__global__ __launch_bounds__(512) void final_kernel(
    const float* __restrict__ ctx, const float* __restrict__ hT,
    const float* __restrict__ Wf0,   // [168][2304]
    const float* __restrict__ bf0,
    const float* __restrict__ Wf1,   // [100][168]
    const float* __restrict__ bf1,
    float* __restrict__ outp)        // [B][100]
{
  int b = blockIdx.x;
  int tid = threadIdx.x;
  int wave = tid >> 6, lane = tid & 63;
  __shared__ float4 xs4[CLSIN / 4];
  __shared__ float zs[F1];
  __shared__ float ls[ETA];
  float* xs = (float*)xs4;
  for (int i = tid; i < NHH * HH; i += 512) xs[i] = ctx[(size_t)b * (NHH * HH) + i];
  if (tid < HH) xs[NHH * HH + tid] = hT[(size_t)b * HH + tid];
  __syncthreads();
  for (int r = wave; r < F1; r += 8) {
    const float4* wp = (const float4*)(Wf0 + (size_t)r * CLSIN);
    float acc = 0.f;
    #pragma unroll
    for (int i = 0; i < CLSIN / 4 / 64; ++i) {  // 9
      float4 w = wp[lane + 64 * i];
      float4 x = xs4[lane + 64 * i];
      acc += w.x * x.x + w.y * x.y + w.z * x.z + w.w * x.w;
    }
    #pragma unroll
    for (int off = 32; off > 0; off >>= 1) acc += __shfl_xor(acc, off, 64);
    if (lane == 0) {
      float x = acc + bf0[r];
      const float alpha = 1.6732632423543772f, scale = 1.0507009873554805f;
      zs[r] = scale * (x > 0.f ? x : alpha * (__expf(x) - 1.f));
    }
  }
  __syncthreads();
  for (int r = wave; r < ETA; r += 8) {
    float acc = 0.f;
    for (int k = lane; k < F1; k += 64) acc += Wf1[r * F1 + k] * zs[k];
    #pragma unroll
    for (int off = 32; off > 0; off >>= 1) acc += __shfl_xor(acc, off, 64);
    if (lane == 0) ls[r] = acc + bf1[r];
  }
  __syncthreads();
  if (wave == 0) {
    float v0 = (lane < ETA) ? ls[lane] : -1e30f;
    float v1 = (lane + 64 < ETA) ? ls[lane + 64] : -1e30f;
    float m = fmaxf(v0, v1);
    #pragma unroll
    for (int off = 32; off > 0; off >>= 1) m = fmaxf(m, __shfl_xor(m, off, 64));
    float s = __expf(v0 - m) + __expf(v1 - m);
    #pragma unroll
    for (int off = 32; off > 0; off >>= 1) s += __shfl_xor(s, off, 64);
    float lse = m + __logf(s);
    if (lane < ETA) outp[(size_t)b * ETA + lane] = v0 - lse;
    if (lane + 64 < ETA) outp[(size_t)b * ETA + lane + 64] = v1 - lse;
  }
}

extern "C" void kernel_launch(void* const* d_in, const int* in_sizes, int n_in,
                              void* d_out, int out_size, void* d_ws, size_t ws_size,
                              hipStream_t stream) {
  const int*   node  = (const int*)d_in[0];
  const float* ts    = (const float*)d_in[1];
  const int*   slen  = (const int*)d_in[2];
  const float* table = (const float*)d_in[3];
  const float* Wih0  = (const float*)d_in[4];
  const float* Whh0  = (const float*)d_in[5];
  const float* bih0  = (const float*)d_in[6];
  const float* bhh0  = (const float*)d_in[7];
  const float* Wih1  = (const float*)d_in[8];
  const float* Whh1  = (const float*)d_in[9];
  const float* bih1  = (const float*)d_in[10];
  const float* bhh1  = (const float*)d_in[11];
  const float* Wa0   = (const float*)d_in[12];
  const float* ba0   = (const float*)d_in[13];
  const float* Wa1   = (const float*)d_in[14];
  const float* ba1   = (const float*)d_in[15];
  const float* Wf0   = (const float*)d_in[16];
  const float* bf0   = (const float*)d_in[17];
  const float* Wf1   = (const float*)d_in[18];
  const float* bf1   = (const float*)d_in[19];

  char* ws = (char*)d_ws;
  size_t off = 0;
  auto alloc = [&](size_t n) { void* p = (void*)(ws + off); off += (n + 255) & ~(size_t)255; return p; };

  half2v* e_h2 = (half2v*)alloc((size_t)LL * BB * 64 * 4);
  float* U     = (float*)alloc((size_t)LL * BB * EE * 4);
  float* V     = (float*)alloc((size_t)LL * BB * EE * 4);
  float* gi    = (float*)alloc((size_t)LL * BB * G3 * 4);   // reused for both layers
  float* out0  = (float*)alloc((size_t)LL * BB * HH * 4);
  float* out1  = (float*)alloc((size_t)LL * BB * HH * 4);
  float* hTb   = (float*)alloc((size_t)BB * HH * 4);
  float* wpre  = (float*)alloc((size_t)LL * BB * NHH * 4);
  float* wsoft = (float*)alloc((size_t)LL * BB * NHH * 4);
  float* ctxb  = (float*)alloc((size_t)BB * NHH * HH * 4);
  half_t* Wa0Ta = (half_t*)alloc((size_t)128 * 128 * 2);
  half_t* Wa0Tb = (half_t*)alloc((size_t)128 * 128 * 2);
  half2v* Wih0T2 = (half2v*)alloc((size_t)65 * 768 * 4);
  half2v* Wih1T2 = (half2v*)alloc((size_t)128 * 768 * 4);
  half_t* Whh0h = (half_t*)alloc((size_t)G3 * HH * 2);
  half_t* Whh1h = (half_t*)alloc((size_t)G3 * HH * 2);
  if (off > ws_size) return;  // workspace too small: fail visibly

  const int prep_total = 16384 + 16384 + 65 * 768 + 128 * 768 + 196608 + 196608;
  prep_kernel<<<(prep_total + 255) / 256, 256, 0, stream>>>(
      Wa0, Wih0, Wih1, Whh0, Whh1, Wa0Ta, Wa0Tb, Wih0T2, Wih1T2, Whh0h, Whh1h);
  embed_uv_kernel<<<LL * BB, 128, 0, stream>>>(node, table, Wa0Ta, Wa0Tb, ba0, e_h2, U, V);
  attn_w_kernel<<<(LL / 4) * BB, 128, 0, stream>>>(U, V, Wa1, ba1, wpre);
  attn_softmax_kernel<<<BB * NHH, 128, 0, stream>>>(wpre, slen, wsoft);
  gi0_kernel<<<LL * BB / 8, 256, 0, stream>>>(e_h2, ts, Wih0T2, bih0, gi);
  gru_scan_kernel<<<BB, 512, 0, stream>>>(Whh0h, bhh0, gi, slen, out0, hTb);
  gi1_kernel<<<LL * BB / 8, 256, 0, stream>>>(out0, Wih1T2, bih1, gi);
  gru_scan_kernel<<<BB, 512, 0, stream>>>(Whh1h, bhh1, gi, slen, out1, hTb);
  ctx_kernel<<<BB * NHH, 256, 0, stream>>>(wsoft, out1, ctxb);
  final_kernel<<<BB, 512, 0, stream>>>(ctxb, hTb, Wf0, bf0, Wf1, bf1, (float*)d_out);
}